// Round 9
// baseline (390.191 us; speedup 1.0000x reference)
//
#include <hip/hip_runtime.h>
#include <cstdint>
#include <cstddef>

typedef unsigned short ushort_t;
typedef __attribute__((ext_vector_type(8))) short s8v;
typedef __attribute__((ext_vector_type(4))) short s4v;
typedef __attribute__((ext_vector_type(4))) float f4v;

#define MFMA16(a, b, c) __builtin_amdgcn_mfma_f32_16x16x32_bf16(a, b, c, 0, 0, 0)

__device__ __forceinline__ ushort_t f2bf(float f) {
  union { float f; unsigned u; } a; a.f = f;
  return (ushort_t)((a.u + 0x7fffu + ((a.u >> 16) & 1u)) >> 16);
}
__device__ __forceinline__ float bf2f(ushort_t h) {
  union { unsigned u; float f; } a; a.u = ((unsigned)h) << 16; return a.f;
}
__device__ __forceinline__ unsigned fbits(float f) {
  union { float f; unsigned u; } a; a.f = f; return a.u;
}

// async global->LDS, 16B per lane; LDS dest is wave-uniform base + lane*16
__device__ __forceinline__ void gload16(const void* g, void* l) {
  __builtin_amdgcn_global_load_lds(
      (__attribute__((address_space(1))) void*)(uintptr_t)g,
      (__attribute__((address_space(3))) void*)(unsigned)(uintptr_t)l,
      16, 0, 0);
}

// ---------------------------------------------------------------------------
// 1) fp32 -> bf16 weight conversion. grid = 12288 blocks x 256 (1024 elem/blk)
// ---------------------------------------------------------------------------
__launch_bounds__(256)
__global__ void convert_w(const float* __restrict__ wq, const float* __restrict__ wk,
                          const float* __restrict__ wv, const float* __restrict__ wo,
                          const float* __restrict__ f1, const float* __restrict__ f2,
                          ushort_t* __restrict__ dqkv, ushort_t* __restrict__ dwo,
                          ushort_t* __restrict__ df1, ushort_t* __restrict__ df2)
{
  const int blk = blockIdx.x;
  const float* src; ushort_t* dst; int off;
  if      (blk < 1024) { src = wq; dst = dqkv;            off = blk; }
  else if (blk < 2048) { src = wk; dst = dqkv + 1048576;  off = blk - 1024; }
  else if (blk < 3072) { src = wv; dst = dqkv + 2097152;  off = blk - 2048; }
  else if (blk < 4096) { src = wo; dst = dwo;             off = blk - 3072; }
  else if (blk < 8192) { src = f1; dst = df1;             off = blk - 4096; }
  else                 { src = f2; dst = df2;             off = blk - 8192; }
  const int idx = off * 1024 + threadIdx.x * 4;
  float4 v = *(const float4*)(src + idx);
  s4v o;
  o[0] = (short)f2bf(v.x); o[1] = (short)f2bf(v.y);
  o[2] = (short)f2bf(v.z); o[3] = (short)f2bf(v.w);
  *(s4v*)(dst + idx) = o;
}

// ---------------------------------------------------------------------------
// 2) adaln: emb[b][j] = sum_d silu(ts[b][d]) * w[j][d] + bias[j]
// ---------------------------------------------------------------------------
__launch_bounds__(256)
__global__ void adaln(const float* __restrict__ ts, const float* __restrict__ w,
                      const float* __restrict__ bias, float* __restrict__ emb)
{
  const int j = blockIdx.x * 4 + (threadIdx.x >> 6);
  const int lane = threadIdx.x & 63;
  const float* wr = w + (size_t)j * 1024;
  float s0 = 0.f, s1 = 0.f;
  for (int i = lane; i < 1024; i += 64) {
    const float wv = wr[i];
    const float t0 = ts[i], t1 = ts[1024 + i];
    const float e0 = __builtin_amdgcn_exp2f(-1.4426950409f * t0);
    const float e1 = __builtin_amdgcn_exp2f(-1.4426950409f * t1);
    s0 += wv * t0 * __builtin_amdgcn_rcpf(1.f + e0);
    s1 += wv * t1 * __builtin_amdgcn_rcpf(1.f + e1);
  }
  #pragma unroll
  for (int m = 32; m; m >>= 1) { s0 += __shfl_down(s0, m); s1 += __shfl_down(s1, m); }
  if (!lane) { emb[j] = s0 + bias[j]; emb[6144 + j] = s1 + bias[j]; }
}

// ---------------------------------------------------------------------------
// 3) LayerNorm + msa modulation -> xm bf16. one block per row.
// ---------------------------------------------------------------------------
__launch_bounds__(256)
__global__ void ln_mod(const float* __restrict__ x, const float* __restrict__ emb,
                       ushort_t* __restrict__ xm)
{
  const int row = blockIdx.x, b = row >> 11, tid = threadIdx.x;
  const float* xr = x + (size_t)row * 1024;
  const int c = tid * 4;
  float4 v = *(const float4*)(xr + c);
  float s  = v.x + v.y + v.z + v.w;
  float s2 = v.x*v.x + v.y*v.y + v.z*v.z + v.w*v.w;
  #pragma unroll
  for (int m = 32; m; m >>= 1) { s += __shfl_down(s, m); s2 += __shfl_down(s2, m); }
  __shared__ float red[8];
  const int wave = tid >> 6, lane = tid & 63;
  if (!lane) { red[wave] = s; red[4 + wave] = s2; }
  __syncthreads();
  const float mu = (red[0] + red[1] + red[2] + red[3]) * (1.f / 1024.f);
  const float ms = (red[4] + red[5] + red[6] + red[7]) * (1.f / 1024.f);
  const float rstd = rsqrtf(ms - mu * mu + 1e-6f);
  const float* sh = emb + b * 6144;
  const float* sc = emb + b * 6144 + 1024;
  float4 shv = *(const float4*)(sh + c);
  float4 scv = *(const float4*)(sc + c);
  s4v ov;
  ov[0] = (short)f2bf((v.x - mu) * rstd * (1.f + scv.x) + shv.x);
  ov[1] = (short)f2bf((v.y - mu) * rstd * (1.f + scv.y) + shv.y);
  ov[2] = (short)f2bf((v.z - mu) * rstd * (1.f + scv.z) + shv.z);
  ov[3] = (short)f2bf((v.w - mu) * rstd * (1.f + scv.w) + shv.w);
  *(s4v*)(xm + (size_t)row * 1024 + c) = ov;
}

// ---------------------------------------------------------------------------
// 4) bf16 B^T GEMM, 128 x TN tile, 4 waves, static dbuf.
//    QKV (EPI=0,TN=128, 768 blocks = 3/CU full fill), WO (1,64), FC2 (3,64).
//    T1 XCD-aware bijective block swizzle (grids %8==0).
// ---------------------------------------------------------------------------
template<int EPI, int TN>
__launch_bounds__(256, 4)
__global__ void gemm_bt(const ushort_t* __restrict__ A, const ushort_t* __restrict__ Bw,
                        int K, int N,
                        ushort_t* __restrict__ outb, float* __restrict__ outf,
                        const float* __restrict__ bias, const float* __restrict__ resid,
                        const float* __restrict__ emb, int gate_off)
{
  constexpr int JN = TN / 32;
  constexpr int BUFB = TN * 32;
  __shared__ ushort_t As0[128 * 32], As1[128 * 32];
  __shared__ ushort_t Bs0[BUFB],    Bs1[BUFB];
  const int tid = threadIdx.x;
  const int wave = tid >> 6, lane = tid & 63;
  const int quad = lane >> 4, r = lane & 15;

  // T1: XCD-aware bijective swizzle (nwg % 8 == 0 for all our grids)
  const int nwg = gridDim.x * gridDim.y;
  int wg = blockIdx.y * gridDim.x + blockIdx.x;
  wg = (wg & 7) * (nwg >> 3) + (wg >> 3);
  const int bx = wg % gridDim.x, by = wg / gridDim.x;
  const int m0 = by * 128, n0 = bx * TN;
  const int wm = (wave >> 1) * 64, wn = (wave & 1) * (TN / 2);

  const int srow = wave * 16 + (lane >> 2);
  const int scol = (lane & 3) * 8;
  const ushort_t* ag = A  + (size_t)(m0 + srow) * K + scol;
  const ushort_t* bg = Bw + (size_t)(n0 + srow) * K + scol;
  const size_t rowK64 = (size_t)64 * K;

  f4v acc[4][JN] = {};

  auto stage = [&](ushort_t* as, ushort_t* bs) {
    gload16(ag,          as + wave * 512);
    gload16(ag + rowK64, as + wave * 512 + 2048);
    gload16(bg,          bs + wave * 512);
    if (TN == 128) gload16(bg + rowK64, bs + wave * 512 + 2048);
    ag += 32; bg += 32;
  };
  auto compute = [&](const ushort_t* ab, const ushort_t* bb) {
    s8v af[4], bf[JN];
    #pragma unroll
    for (int i = 0; i < 4; i++)
      af[i] = *(const s8v*)(ab + (wm + i * 16 + r) * 32 + quad * 8);
    #pragma unroll
    for (int j = 0; j < JN; j++)
      bf[j] = *(const s8v*)(bb + (wn + j * 16 + r) * 32 + quad * 8);
    #pragma unroll
    for (int i = 0; i < 4; i++)
      #pragma unroll
      for (int j = 0; j < JN; j++)
        acc[i][j] = MFMA16(af[i], bf[j], acc[i][j]);
  };

  stage(As0, Bs0);
  __syncthreads();
  const int R = (K >> 6) - 1;
  for (int it = 0; it < R; it++) {
    stage(As1, Bs1);
    compute(As0, Bs0);
    __syncthreads();
    stage(As0, Bs0);
    compute(As1, Bs1);
    __syncthreads();
  }
  stage(As1, Bs1);
  compute(As0, Bs0);
  __syncthreads();
  compute(As1, Bs1);

  const int bblk = m0 >> 11;
  float bj[JN], gj[JN];
  #pragma unroll
  for (int j = 0; j < JN; j++) {
    const int col = n0 + wn + j * 16 + r;
    bj[j] = (EPI == 2 || EPI == 3) ? bias[col] : 0.f;
    gj[j] = (EPI == 1 || EPI == 3) ? emb[bblk * 6144 + gate_off + col] : 0.f;
  }
  #pragma unroll
  for (int i = 0; i < 4; i++) {
    #pragma unroll
    for (int rr = 0; rr < 4; rr++) {
      const int row = m0 + wm + i * 16 + quad * 4 + rr;
      const size_t rbase = (size_t)row * N + n0 + wn;
      #pragma unroll
      for (int j = 0; j < JN; j++) {
        float v = acc[i][j][rr];
        const size_t idx = rbase + j * 16 + r;
        if (EPI == 0) {
          outb[idx] = f2bf(v);
        } else if (EPI == 1) {
          outf[idx] = resid[idx] + gj[j] * v;
        } else if (EPI == 2) {
          v += bj[j];
          const float t = fmaf(v * v, 0.1029436f, 2.3022083f);
          const float e = __builtin_amdgcn_exp2f(-v * t);
          outb[idx] = f2bf(v * __builtin_amdgcn_rcpf(1.f + e));
        } else {
          outf[idx] = resid[idx] + gj[j] * (v + bj[j]);
        }
      }
    }
  }
}

// ---------------------------------------------------------------------------
// 4c) gemm8p v2 (R7 best-measured): fine-interleave 8-phase, 256x256 tile,
//     BK=64, 512 threads = 8 waves (2M x 4N), dbuf LDS 128KB.
//     Used for FC1 ONLY (grid 256 = exact 1 block/CU fill; QKV's 192-block
//     grid idles 25% of CUs -> QKV stays on gemm_bt).
// ---------------------------------------------------------------------------
#define G8P(AB, BB, SDA, SDB, KO, STG, P)                                     \
  {                                                                           \
    s8v af0k0, af0k1, af1k0, af1k1;                                           \
    {                                                                         \
      const ushort_t* Ap0 = (AB) + (size_t)(wm + (2*(P)) * 16 + r) * 64;      \
      const ushort_t* Ap1 = (AB) + (size_t)(wm + (2*(P)+1) * 16 + r) * 64;    \
      af0k0 = *(const s8v*)(Ap0 + ((quad ^ rx) << 3));                        \
      af0k1 = *(const s8v*)(Ap0 + (((4 + quad) ^ rx) << 3));                  \
      af1k0 = *(const s8v*)(Ap1 + ((quad ^ rx) << 3));                        \
      af1k1 = *(const s8v*)(Ap1 + (((4 + quad) ^ rx) << 3));                  \
    }                                                                         \
    if ((P) == 0) {                                                           \
      _Pragma("unroll")                                                       \
      for (int j_ = 0; j_ < 4; j_++) {                                        \
        const ushort_t* Bp = (BB) + (size_t)(wn + j_ * 16 + r) * 64;          \
        bfv[j_][0] = *(const s8v*)(Bp + ((quad ^ rx) << 3));                  \
        bfv[j_][1] = *(const s8v*)(Bp + (((4 + quad) ^ rx) << 3));            \
      }                                                                       \
    }                                                                         \
    if (STG) {                                                                \
      gload16(ag + (KO) + (P) * row8K, (SDA) + (P) * 512);                    \
      gload16(bg + (KO) + (P) * row8K, (SDB) + (P) * 512);                    \
    }                                                                         \
    __builtin_amdgcn_s_barrier();                                             \
    asm volatile("s_waitcnt lgkmcnt(0)" ::: "memory");                        \
    __builtin_amdgcn_sched_barrier(0);                                        \
    __builtin_amdgcn_s_setprio(1);                                            \
    _Pragma("unroll")                                                         \
    for (int j_ = 0; j_ < 4; j_++) {                                          \
      acc[2*(P)][j_]     = MFMA16(af0k0, bfv[j_][0], acc[2*(P)][j_]);         \
      acc[2*(P)][j_]     = MFMA16(af0k1, bfv[j_][1], acc[2*(P)][j_]);         \
      acc[2*(P)+1][j_]   = MFMA16(af1k0, bfv[j_][0], acc[2*(P)+1][j_]);       \
      acc[2*(P)+1][j_]   = MFMA16(af1k1, bfv[j_][1], acc[2*(P)+1][j_]);       \
    }                                                                         \
    __builtin_amdgcn_s_setprio(0);                                            \
    __builtin_amdgcn_s_barrier();                                             \
  }

template<int EPI>
__launch_bounds__(512, 2)
__global__ void gemm8p(const ushort_t* __restrict__ A, const ushort_t* __restrict__ Bw,
                       int K, int N, ushort_t* __restrict__ outb,
                       const float* __restrict__ bias)
{
  __shared__ ushort_t Ash[2][256 * 64];   // [buf][row][chunk^(row&7)], 64KB
  __shared__ ushort_t Bsh[2][256 * 64];
  const int tid = threadIdx.x;
  const int wid = tid >> 6, lane = tid & 63;
  const int quad = lane >> 4, r = lane & 15, rx = r & 7;

  // T1: XCD-aware bijective block swizzle (nwg % 8 == 0 for our grids)
  const int nwg = gridDim.x * gridDim.y;
  int wg = blockIdx.y * gridDim.x + blockIdx.x;
  wg = (wg & 7) * (nwg >> 3) + (wg >> 3);
  const int bx = wg % gridDim.x, by = wg / gridDim.x;
  const int m0 = by * 256, n0 = bx * 256;
  const int wm = (wid >> 2) * 128;   // wave row base in tile
  const int wn = (wid & 3) * 64;     // wave col base in tile

  // staging: lane l covers row (l>>3), 16B slot (l&7); LDS slot s of row r
  // holds logical chunk s^(r&7) -> inverse-swizzle the global SOURCE col.
  const int srow = lane >> 3;
  const int scol = ((lane & 7) ^ srow) * 8;
  const ushort_t* ag = A  + (size_t)(m0 + wid * 32 + srow) * K + scol;
  const ushort_t* bg = Bw + (size_t)(n0 + wid * 32 + srow) * K + scol;
  const size_t row8K = (size_t)8 * K;

  ushort_t* A0d = &Ash[0][wid * 2048];
  ushort_t* B0d = &Bsh[0][wid * 2048];
  ushort_t* A1d = &Ash[1][wid * 2048];
  ushort_t* B1d = &Bsh[1][wid * 2048];

  f4v acc[8][4] = {};

  // prologue: stage tile 0 fully into buf0
  #pragma unroll
  for (int c = 0; c < 4; c++) {
    gload16(ag + c * row8K, A0d + c * 512);
    gload16(bg + c * row8K, B0d + c * 512);
  }
  __syncthreads();

  const int NT = K >> 6;   // even, >= 4 for our shapes
  #pragma unroll 1
  for (int t = 0; t < NT; t += 2) {
    {
      // tile t: compute buf0, stage t+1 -> buf1 (2 loads per phase)
      const ushort_t* Ab = &Ash[0][0];
      const ushort_t* Bb = &Bsh[0][0];
      const size_t ko = (size_t)(t + 1) * 64;
      s8v bfv[4][2];
      G8P(Ab, Bb, A1d, B1d, ko, true, 0);
      G8P(Ab, Bb, A1d, B1d, ko, true, 1);
      G8P(Ab, Bb, A1d, B1d, ko, true, 2);
      G8P(Ab, Bb, A1d, B1d, ko, true, 3);
      __syncthreads();   // drain: t+1's loads (issued ph0-3) + barrier
    }
    {
      // tile t+1: compute buf1, stage t+2 -> buf0 (if it exists)
      const ushort_t* Ab = &Ash[1][0];
      const ushort_t* Bb = &Bsh[1][0];
      const size_t ko = (size_t)(t + 2) * 64;
      const bool stg = (t + 2) < NT;
      s8v bfv[4][2];
      G8P(Ab, Bb, A0d, B0d, ko, stg, 0);
      G8P(Ab, Bb, A0d, B0d, ko, stg, 1);
      G8P(Ab, Bb, A0d, B0d, ko, stg, 2);
      G8P(Ab, Bb, A0d, B0d, ko, stg, 3);
      __syncthreads();
    }
  }

  // epilogue (row-outer, j-inner for full-line write combining)
  float bj[4];
  #pragma unroll
  for (int j = 0; j < 4; j++)
    bj[j] = (EPI == 2) ? bias[n0 + wn + j * 16 + r] : 0.f;
  #pragma unroll
  for (int i = 0; i < 8; i++) {
    #pragma unroll
    for (int rr = 0; rr < 4; rr++) {
      const int row = m0 + wm + i * 16 + quad * 4 + rr;
      const size_t rbase = (size_t)row * N + n0 + wn;
      #pragma unroll
      for (int j = 0; j < 4; j++) {
        float v = acc[i][j][rr];
        const size_t idx = rbase + j * 16 + r;
        if (EPI == 0) {
          outb[idx] = f2bf(v);
        } else {
          v += bj[j];
          const float tt = fmaf(v * v, 0.1029436f, 2.3022083f);
          const float e = __builtin_amdgcn_exp2f(-v * tt);
          outb[idx] = f2bf(v * __builtin_amdgcn_rcpf(1.f + e));
        }
      }
    }
  }
}

// ---------------------------------------------------------------------------
// 5) QKV post: RMSNorm + RoPE + layout.
// ---------------------------------------------------------------------------
__launch_bounds__(256)
__global__ void qkv_post(const ushort_t* __restrict__ qkv, const float* __restrict__ rope,
                         const float* __restrict__ qw, const float* __restrict__ kw,
                         ushort_t* __restrict__ q_r, ushort_t* __restrict__ k_r,
                         ushort_t* __restrict__ v_r)
{
  const int row = blockIdx.x, b = row >> 11, s = row & 2047, tid = threadIdx.x;
  const ushort_t* base = qkv + (size_t)row * 3072;
  const int c = tid * 4;
  s4v qv = *(const s4v*)(base + c);
  s4v kv = *(const s4v*)(base + 1024 + c);
  s4v vv = *(const s4v*)(base + 2048 + c);
  float qf[4], kf[4]; float sq = 0.f, sk = 0.f;
  #pragma unroll
  for (int i = 0; i < 4; i++) {
    qf[i] = bf2f((ushort_t)qv[i]); kf[i] = bf2f((ushort_t)kv[i]);
    sq += qf[i] * qf[i]; sk += kf[i] * kf[i];
  }
  #pragma unroll
  for (int m = 32; m; m >>= 1) { sq += __shfl_down(sq, m); sk += __shfl_down(sk, m); }
  __shared__ float red[8];
  const int wave = tid >> 6, lane = tid & 63;
  if (!lane) { red[wave] = sq; red[4 + wave] = sk; }
  __syncthreads();
  const float rq = rsqrtf((red[0]+red[1]+red[2]+red[3]) * (1.f/1024.f) + 1e-6f)
                   * 0.18033688011112042f;  // fold 0.125*log2(e) into Q
  const float rk = rsqrtf((red[4]+red[5]+red[6]+red[7]) * (1.f/1024.f) + 1e-6f);

  const int h = c >> 6, d = c & 63;
  const float* rp = rope + ((size_t)s * 64 + d) * 2;
  float4 r01 = *(const float4*)(rp);
  float4 r23 = *(const float4*)(rp + 4);
  const float q0 = qf[0]*rq*qw[c], q1 = qf[1]*rq*qw[c+1];
  const float q2 = qf[2]*rq*qw[c+2], q3 = qf[3]*rq*qw[c+3];
  const float k0 = kf[0]*rk*kw[c], k1 = kf[1]*rk*kw[c+1];
  const float k2 = kf[2]*rk*kw[c+2], k3 = kf[3]*rk*kw[c+3];
  s4v qo, ko;
  qo[0] = (short)f2bf(q0 * r01.x - q1 * r01.y);
  qo[1] = (short)f2bf(q1 * r01.z + q0 * r01.w);
  qo[2] = (short)f2bf(q2 * r23.x - q3 * r23.y);
  qo[3] = (short)f2bf(q3 * r23.z + q2 * r23.w);
  ko[0] = (short)f2bf(k0 * r01.x - k1 * r01.y);
  ko[1] = (short)f2bf(k1 * r01.z + k0 * r01.w);
  ko[2] = (short)f2bf(k2 * r23.x - k3 * r23.y);
  ko[3] = (short)f2bf(k3 * r23.z + k2 * r23.w);
  const size_t rowbase = ((size_t)(b * 16 + h) * 2048 + s) * 64;
  const int d_s = (((d >> 3) ^ (s & 7)) << 3) | (d & 7);   // K chunk swizzle
  *(s4v*)(q_r + rowbase + d) = qo;
  *(s4v*)(k_r + rowbase + d_s) = ko;
  *(s4v*)(v_r + rowbase + d) = vv;
}

// ---------------------------------------------------------------------------
// 6) V transpose.
// ---------------------------------------------------------------------------
__launch_bounds__(256)
__global__ void vtrans(const ushort_t* __restrict__ v_r, ushort_t* __restrict__ v_t)
{
  const int bh = blockIdx.x >> 5, st = blockIdx.x & 31;
  const int s0 = st * 64;
  __shared__ ushort_t tile[64 * 72];
  const int tid = threadIdx.x;
  #pragma unroll
  for (int rep = 0; rep < 2; rep++) {
    const int idx = rep * 256 + tid;
    const int sr = idx >> 3, dc = (idx & 7) << 3;
    s8v val = *(const s8v*)(v_r + ((size_t)bh * 2048 + s0 + sr) * 64 + dc);
    *(s8v*)(tile + sr * 72 + dc) = val;
  }
  __syncthreads();
  #pragma unroll
  for (int rep = 0; rep < 2; rep++) {
    const int idx = rep * 256 + tid;
    const int d = idx >> 3;
    const int scs = (((idx & 7) ^ (d & 7)) << 3);
    s8v val;
    const int sc = (idx & 7) << 3;
    #pragma unroll
    for (int j = 0; j < 8; j++) val[j] = (short)tile[(sc + j) * 72 + d];
    *(s8v*)(v_t + ((size_t)bh * 64 + d) * 2048 + s0 + scs) = val;
  }
}

// ---------------------------------------------------------------------------
// 7) Flash attention, v7 (frozen): KVBLK=64, K+V dbuf LDS 40KB,
//    4 blocks/CU, defer-max (T13).
// ---------------------------------------------------------------------------
__launch_bounds__(256, 4)
__global__ void flash(const ushort_t* __restrict__ q_r, const ushort_t* __restrict__ k_r,
                      const ushort_t* __restrict__ v_t, ushort_t* __restrict__ attn)
{
  __shared__ ushort_t Ksh[2][64 * 64];   // [key][d], 8 chunks ^(key&7), x2 dbuf
  __shared__ ushort_t Vsh[2][64 * 64];   // [d][key], 8 chunks pos = c^(d&7), x2 dbuf
  __shared__ ushort_t Psh[4][16 * 64];   // per-wave [q][key], chunk pos = c^(q&7)
  const int bh = blockIdx.x >> 5, qb = blockIdx.x & 31;
  const int tid = threadIdx.x, wave = tid >> 6, lane = tid & 63;
  const int quad = lane >> 4, r = lane & 15;
  const int rx = r & 7;
  const int q0 = qb * 64 + wave * 16;
  const size_t bhS = (size_t)bh * 2048;

  s8v aq0 = *(const s8v*)(q_r + (bhS + q0 + r) * 64 + quad * 8);
  s8v aq1 = *(const s8v*)(q_r + (bhS + q0 + r) * 64 + 32 + quad * 8);

  f4v o[4] = {};
  float mi = -1e30f, li = 0.f;

  // staging: per wave 16 K-rows (2 calls x 8 rows) and 16 V-rows (2 x 8)
  const ushort_t* kg = k_r + (bhS + wave * 16 + (lane >> 3)) * 64 + (lane & 7) * 8;
  const ushort_t* vg = v_t + ((size_t)bh * 64 + wave * 16 + (lane >> 3)) * 2048
                       + (lane & 7) * 8;
  const int klo = wave * 1024 + lane * 8;   // = wave-base + lane*16B
  const int vlo = wave * 1024 + lane * 8;
  ushort_t* pw = &Psh[wave][0];

  auto stage = [&](ushort_t* kbuf, ushort_t* vbuf, int kb) {
    #pragma unroll
    for (int c = 0; c < 2; c++) {
      gload16(kg + (size_t)(kb + c * 8) * 64, kbuf + klo + c * 512);
      gload16(vg + kb + (size_t)(c * 8) * 2048, vbuf + vlo + c * 512);
    }
  };

  // QK^T -> online softmax (defer-max) -> PV on one staged 64-key tile
  auto step = [&](const ushort_t* Kc, const ushort_t* Vc) {
    // S^T[key][q]: 4 row-tiles of 16 keys
    f4v st[4];
    __builtin_amdgcn_s_setprio(1);
    #pragma unroll
    for (int t = 0; t < 4; t++) {
      const ushort_t* krow = Kc + (t * 16 + r) * 64;
      s8v k0 = *(const s8v*)(krow + ((quad ^ rx) << 3));
      s8v k1 = *(const s8v*)(krow + (((4 + quad) ^ rx) << 3));
      f4v z = {};
      z = MFMA16(k0, aq0, z);
      z = MFMA16(k1, aq1, z);
      st[t] = z;
    }
    __builtin_amdgcn_s_setprio(0);

    // max: tree + 2 cross-lane hops
    float m4[4];
    #pragma unroll
    for (int t = 0; t < 4; t++)
      m4[t] = fmaxf(fmaxf(st[t][0], st[t][1]), fmaxf(st[t][2], st[t][3]));
    float mloc = fmaxf(fmaxf(m4[0], m4[1]), fmaxf(m4[2], m4[3]));
    mloc = fmaxf(mloc, __shfl_xor(mloc, 16));
    mloc = fmaxf(mloc, __shfl_xor(mloc, 32));

    // defer-max: if no q-row grew its max by > 8, keep old mi (skip rescale)
    const bool grow = !__all(mloc - mi <= 8.f);
    const float mref = grow ? fmaxf(mi, mloc) : mi;

    float p[4][4];
    uint2 pk[4];
    #pragma unroll
    for (int t = 0; t < 4; t++) {
      #pragma unroll
      for (int rr = 0; rr < 4; rr++)
        p[t][rr] = __builtin_amdgcn_exp2f(st[t][rr] - mref);
      const unsigned u0 = fbits(p[t][0]) + 0x8000u;
      const unsigned u1 = fbits(p[t][1]) + 0x8000u;
      const unsigned u2 = fbits(p[t][2]) + 0x8000u;
      const unsigned u3 = fbits(p[t][3]) + 0x8000u;
      pk[t].x = __builtin_amdgcn_perm(u1, u0, 0x07060302u);
      pk[t].y = __builtin_amdgcn_perm(u3, u2, 0x07060302u);
    }

    // pack P -> Psh (8 chunks, swizzled), b64 writes
    #pragma unroll
    for (int t = 0; t < 4; t++) {
      const int cw = t * 2 + (quad >> 1);     // logical chunk 0..7
      const int sc = cw ^ rx;
      *(uint2*)(pw + r * 64 + (sc << 3) + (quad & 1) * 4) = pk[t];
    }

    // rescale O only when the running max actually moved
    if (grow) {
      const float al = __builtin_amdgcn_exp2f(mi - mref);
      float alo[4];
      #pragma unroll
      for (int rr = 0; rr < 4; rr++) alo[rr] = __shfl(al, quad * 4 + rr);
      #pragma unroll
      for (int nt = 0; nt < 4; nt++)
        #pragma unroll
        for (int rr = 0; rr < 4; rr++) o[nt][rr] *= alo[rr];
      li *= al;
      mi = mref;
    }

    // sum: tree + 2 hops
    float s4r[4];
    #pragma unroll
    for (int t = 0; t < 4; t++)
      s4r[t] = (p[t][0] + p[t][1]) + (p[t][2] + p[t][3]);
    float ls = (s4r[0] + s4r[1]) + (s4r[2] + s4r[3]);
    ls += __shfl_xor(ls, 16);
    ls += __shfl_xor(ls, 32);
    li += ls;

    asm volatile("s_waitcnt lgkmcnt(0)" ::: "memory");  // P writes -> reads, same wave

    // O += P * V  (K = 32 keys per MFMA, 2 chunks of the 64-key tile)
    __builtin_amdgcn_s_setprio(1);
    #pragma unroll
    for (int kc = 0; kc < 2; kc++) {
      const int c = kc * 4 + quad;           // logical chunk 0..7
      const int sc = c ^ rx;
      s8v ap = *(const s8v*)(pw + r * 64 + (sc << 3));
      #pragma unroll
      for (int nt = 0; nt < 4; nt++) {
        s8v bv = *(const s8v*)(Vc + (nt * 16 + r) * 64 + (sc << 3));
        o[nt] = MFMA16(ap, bv, o[nt]);
      }
    }
    __builtin_amdgcn_s_setprio(0);
  };

  // prologue: stage tile 0; __syncthreads drains vmcnt(0) + barrier
  stage(Ksh[0], Vsh[0], 0);
  __syncthreads();

  // 32 tiles, 2 per iteration (static buffer indices).
  #pragma unroll 1
  for (int kb = 0; kb < 2048; kb += 128) {
    stage(Ksh[1], Vsh[1], kb + 64);
    step(Ksh[0], Vsh[0]);
    __syncthreads();
    if (kb + 128 < 2048) stage(Ksh[0], Vsh[0], kb + 128);
    step(Ksh[1], Vsh[1]);
    __syncthreads();
  }

  const int h = bh & 15, b = bh >> 4;
  const float linv = 1.f / li;
  #pragma unroll
  for (int rr = 0; rr < 4; rr++) {
    const float inv = __shfl(linv, quad * 4 + rr);
    const size_t orow = ((size_t)(b * 2048 + q0 + quad * 4 + rr)) * 1024 + h * 64;
    #pragma unroll
    for (int nt = 0; nt < 4; nt++)
      attn[orow + nt * 16 + r] = f2bf(o[nt][rr] * inv);
  }
}

// ---------------------------------------------------------------------------
// 8) RMSNorm3 + mlp modulation -> nm bf16
// ---------------------------------------------------------------------------
__launch_bounds__(256)
__global__ void rms3_mod(const float* __restrict__ h, const float* __restrict__ emb,
                         const float* __restrict__ w3, ushort_t* __restrict__ nm)
{
  const int row = blockIdx.x, b = row >> 11, tid = threadIdx.x;
  const float* hr = h + (size_t)row * 1024;
  const int c = tid * 4;
  float4 v = *(const float4*)(hr + c);
  float s2 = v.x*v.x + v.y*v.y + v.z*v.z + v.w*v.w;
  #pragma unroll
  for (int m = 32; m; m >>= 1) s2 += __shfl_down(s2, m);
  __shared__ float red[4];
  const int wave = tid >> 6, lane = tid & 63;
  if (!lane) red[wave] = s2;
  __syncthreads();
  const float rms = rsqrtf((red[0] + red[1] + red[2] + red[3]) * (1.f / 1024.f) + 1e-6f);
  const float* sh = emb + b * 6144 + 3072;
  const float* sc = emb + b * 6144 + 4096;
  float4 shv = *(const float4*)(sh + c);
  float4 scv = *(const float4*)(sc + c);
  float4 wv  = *(const float4*)(w3 + c);
  s4v ov;
  ov[0] = (short)f2bf(v.x * rms * wv.x * (1.f + scv.x) + shv.x);
  ov[1] = (short)f2bf(v.y * rms * wv.y * (1.f + scv.y) + shv.y);
  ov[2] = (short)f2bf(v.z * rms * wv.z * (1.f + scv.z) + shv.z);
  ov[3] = (short)f2bf(v.w * rms * wv.w * (1.f + scv.w) + shv.w);
  *(s4v*)(nm + (size_t)row * 1024 + c) = ov;
}

// ---------------------------------------------------------------------------
// host launcher
// ---------------------------------------------------------------------------
extern "C" void kernel_launch(void* const* d_in, const int* in_sizes, int n_in,
                              void* d_out, int out_size, void* d_ws, size_t ws_size,
                              hipStream_t stream)
{
  const float* x    = (const float*)d_in[0];
  const float* ts   = (const float*)d_in[1];
  const float* rope = (const float*)d_in[2];
  const float* adw  = (const float*)d_in[3];
  const float* adb  = (const float*)d_in[4];
  const float* wq   = (const float*)d_in[5];
  const float* wk   = (const float*)d_in[6];
  const float* wv   = (const float*)d_in[7];
  const float* wo   = (const float*)d_in[8];
  const float* qnw  = (const float*)d_in[9];
  const float* knw  = (const float*)d_in[10];
  const float* n3w  = (const float*)d_in[11];
  const float* f1w  = (const float*)d_in[12];
  const float* f1b  = (const float*)d_in[13];
  const float* f2w  = (const float*)d_in[14];
  const float* f2b  = (const float*)d_in[15];

  char* ws = (char*)d_ws;
  ushort_t* WQKV = (ushort_t*)(ws + 0);          //  6 MB
  ushort_t* WO   = (ushort_t*)(ws + 6291456);    //  2 MB
  ushort_t* F1   = (ushort_t*)(ws + 8388608);    //  8 MB
  ushort_t* F2   = (ushort_t*)(ws + 16777216);   //  8 MB
  float*    EMB  = (float*)   (ws + 25165824);   //  48 KB
  float*    H    = (float*)   (ws + 25214976);   // 16 MB
  ushort_t* XM   = (ushort_t*)(ws + 41992192);   //  8 MB  (later: ATTN)
  ushort_t* QKV  = (ushort_t*)(ws + 50380800);   // 24 MB  (later: NM)
  ushort_t* QR   = (ushort_t*)(ws + 75546624);   //  8 MB  (later: FF1 spans 32MB)
  ushort_t* KR   = (ushort_t*)(ws + 83935232);   //  8 MB
  ushort_t* VR   = (ushort_t*)(ws + 92323840);   //  8 MB
  ushort_t* VT   = (ushort_t*)(ws + 100712448);  //  8 MB
  ushort_t* ATTN = XM;
  ushort_t* NM   = QKV;
  ushort_t* FF1  = QR;

  convert_w<<<12288, 256, 0, stream>>>(wq, wk, wv, wo, f1w, f2w, WQKV, WO, F1, F2);
  adaln<<<1536, 256, 0, stream>>>(ts, adw, adb, EMB);
  ln_mod<<<4096, 256, 0, stream>>>(x, EMB, XM);
  gemm_bt<0, 128><<<dim3(24, 32), 256, 0, stream>>>(XM, WQKV, 1024, 3072,
      QKV, nullptr, nullptr, nullptr, nullptr, 0);
  qkv_post<<<4096, 256, 0, stream>>>(QKV, rope, qnw, knw, QR, KR, VR);
  vtrans<<<1024, 256, 0, stream>>>(VR, VT);
  flash<<<1024, 256, 0, stream>>>(QR, KR, VT, ATTN);
  gemm_bt<1, 64><<<dim3(16, 32), 256, 0, stream>>>(ATTN, WO, 1024, 1024,
      nullptr, H, nullptr, x, EMB, 2048);
  rms3_mod<<<4096, 256, 0, stream>>>(H, EMB, n3w, NM);
  gemm8p<2><<<dim3(16, 16), 512, 0, stream>>>(NM, F1, 1024, 4096, FF1, f1b);
  gemm_bt<3, 64><<<dim3(16, 32), 256, 0, stream>>>(FF1, F2, 4096, 1024,
      nullptr, (float*)d_out, f2b, H, EMB, 5120);
}

// Round 10
// 384.586 us; speedup vs baseline: 1.0146x; 1.0146x over previous
//
#include <hip/hip_runtime.h>
#include <cstdint>
#include <cstddef>

typedef unsigned short ushort_t;
typedef __attribute__((ext_vector_type(8))) short s8v;
typedef __attribute__((ext_vector_type(4))) short s4v;
typedef __attribute__((ext_vector_type(4))) float f4v;

#define MFMA16(a, b, c) __builtin_amdgcn_mfma_f32_16x16x32_bf16(a, b, c, 0, 0, 0)

__device__ __forceinline__ ushort_t f2bf(float f) {
  union { float f; unsigned u; } a; a.f = f;
  return (ushort_t)((a.u + 0x7fffu + ((a.u >> 16) & 1u)) >> 16);
}
__device__ __forceinline__ float bf2f(ushort_t h) {
  union { unsigned u; float f; } a; a.u = ((unsigned)h) << 16; return a.f;
}
__device__ __forceinline__ unsigned fbits(float f) {
  union { float f; unsigned u; } a; a.f = f; return a.u;
}

// async global->LDS, 16B per lane; LDS dest is wave-uniform base + lane*16
__device__ __forceinline__ void gload16(const void* g, void* l) {
  __builtin_amdgcn_global_load_lds(
      (__attribute__((address_space(1))) void*)(uintptr_t)g,
      (__attribute__((address_space(3))) void*)(unsigned)(uintptr_t)l,
      16, 0, 0);
}

// ---------------------------------------------------------------------------
// 1) fp32 -> bf16 weight conversion. grid = 12288 blocks x 256 (1024 elem/blk)
// ---------------------------------------------------------------------------
__launch_bounds__(256)
__global__ void convert_w(const float* __restrict__ wq, const float* __restrict__ wk,
                          const float* __restrict__ wv, const float* __restrict__ wo,
                          const float* __restrict__ f1, const float* __restrict__ f2,
                          ushort_t* __restrict__ dqkv, ushort_t* __restrict__ dwo,
                          ushort_t* __restrict__ df1, ushort_t* __restrict__ df2)
{
  const int blk = blockIdx.x;
  const float* src; ushort_t* dst; int off;
  if      (blk < 1024) { src = wq; dst = dqkv;            off = blk; }
  else if (blk < 2048) { src = wk; dst = dqkv + 1048576;  off = blk - 1024; }
  else if (blk < 3072) { src = wv; dst = dqkv + 2097152;  off = blk - 2048; }
  else if (blk < 4096) { src = wo; dst = dwo;             off = blk - 3072; }
  else if (blk < 8192) { src = f1; dst = df1;             off = blk - 4096; }
  else                 { src = f2; dst = df2;             off = blk - 8192; }
  const int idx = off * 1024 + threadIdx.x * 4;
  float4 v = *(const float4*)(src + idx);
  s4v o;
  o[0] = (short)f2bf(v.x); o[1] = (short)f2bf(v.y);
  o[2] = (short)f2bf(v.z); o[3] = (short)f2bf(v.w);
  *(s4v*)(dst + idx) = o;
}

// ---------------------------------------------------------------------------
// 2) adaln: emb[b][j] = sum_d silu(ts[b][d]) * w[j][d] + bias[j]
// ---------------------------------------------------------------------------
__launch_bounds__(256)
__global__ void adaln(const float* __restrict__ ts, const float* __restrict__ w,
                      const float* __restrict__ bias, float* __restrict__ emb)
{
  const int j = blockIdx.x * 4 + (threadIdx.x >> 6);
  const int lane = threadIdx.x & 63;
  const float* wr = w + (size_t)j * 1024;
  float s0 = 0.f, s1 = 0.f;
  for (int i = lane; i < 1024; i += 64) {
    const float wv = wr[i];
    const float t0 = ts[i], t1 = ts[1024 + i];
    const float e0 = __builtin_amdgcn_exp2f(-1.4426950409f * t0);
    const float e1 = __builtin_amdgcn_exp2f(-1.4426950409f * t1);
    s0 += wv * t0 * __builtin_amdgcn_rcpf(1.f + e0);
    s1 += wv * t1 * __builtin_amdgcn_rcpf(1.f + e1);
  }
  #pragma unroll
  for (int m = 32; m; m >>= 1) { s0 += __shfl_down(s0, m); s1 += __shfl_down(s1, m); }
  if (!lane) { emb[j] = s0 + bias[j]; emb[6144 + j] = s1 + bias[j]; }
}

// ---------------------------------------------------------------------------
// 3) LayerNorm + msa modulation -> xm bf16. one block per row.
// ---------------------------------------------------------------------------
__launch_bounds__(256)
__global__ void ln_mod(const float* __restrict__ x, const float* __restrict__ emb,
                       ushort_t* __restrict__ xm)
{
  const int row = blockIdx.x, b = row >> 11, tid = threadIdx.x;
  const float* xr = x + (size_t)row * 1024;
  const int c = tid * 4;
  float4 v = *(const float4*)(xr + c);
  float s  = v.x + v.y + v.z + v.w;
  float s2 = v.x*v.x + v.y*v.y + v.z*v.z + v.w*v.w;
  #pragma unroll
  for (int m = 32; m; m >>= 1) { s += __shfl_down(s, m); s2 += __shfl_down(s2, m); }
  __shared__ float red[8];
  const int wave = tid >> 6, lane = tid & 63;
  if (!lane) { red[wave] = s; red[4 + wave] = s2; }
  __syncthreads();
  const float mu = (red[0] + red[1] + red[2] + red[3]) * (1.f / 1024.f);
  const float ms = (red[4] + red[5] + red[6] + red[7]) * (1.f / 1024.f);
  const float rstd = rsqrtf(ms - mu * mu + 1e-6f);
  const float* sh = emb + b * 6144;
  const float* sc = emb + b * 6144 + 1024;
  float4 shv = *(const float4*)(sh + c);
  float4 scv = *(const float4*)(sc + c);
  s4v ov;
  ov[0] = (short)f2bf((v.x - mu) * rstd * (1.f + scv.x) + shv.x);
  ov[1] = (short)f2bf((v.y - mu) * rstd * (1.f + scv.y) + shv.y);
  ov[2] = (short)f2bf((v.z - mu) * rstd * (1.f + scv.z) + shv.z);
  ov[3] = (short)f2bf((v.w - mu) * rstd * (1.f + scv.w) + shv.w);
  *(s4v*)(xm + (size_t)row * 1024 + c) = ov;
}

// ---------------------------------------------------------------------------
// 4) bf16 B^T GEMM, 128 x TN tile, 4 waves, static dbuf. WO (EPI=1) / FC2 (3).
//    T1 XCD-aware bijective block swizzle (grids %8==0).
// ---------------------------------------------------------------------------
template<int EPI, int TN>
__launch_bounds__(256, 4)
__global__ void gemm_bt(const ushort_t* __restrict__ A, const ushort_t* __restrict__ Bw,
                        int K, int N,
                        ushort_t* __restrict__ outb, float* __restrict__ outf,
                        const float* __restrict__ bias, const float* __restrict__ resid,
                        const float* __restrict__ emb, int gate_off)
{
  constexpr int JN = TN / 32;
  constexpr int BUFB = TN * 32;
  __shared__ ushort_t As0[128 * 32], As1[128 * 32];
  __shared__ ushort_t Bs0[BUFB],    Bs1[BUFB];
  const int tid = threadIdx.x;
  const int wave = tid >> 6, lane = tid & 63;
  const int quad = lane >> 4, r = lane & 15;

  // T1: XCD-aware bijective swizzle (nwg % 8 == 0 for all our grids)
  const int nwg = gridDim.x * gridDim.y;
  int wg = blockIdx.y * gridDim.x + blockIdx.x;
  wg = (wg & 7) * (nwg >> 3) + (wg >> 3);
  const int bx = wg % gridDim.x, by = wg / gridDim.x;
  const int m0 = by * 128, n0 = bx * TN;
  const int wm = (wave >> 1) * 64, wn = (wave & 1) * (TN / 2);

  const int srow = wave * 16 + (lane >> 2);
  const int scol = (lane & 3) * 8;
  const ushort_t* ag = A  + (size_t)(m0 + srow) * K + scol;
  const ushort_t* bg = Bw + (size_t)(n0 + srow) * K + scol;
  const size_t rowK64 = (size_t)64 * K;

  f4v acc[4][JN] = {};

  auto stage = [&](ushort_t* as, ushort_t* bs) {
    gload16(ag,          as + wave * 512);
    gload16(ag + rowK64, as + wave * 512 + 2048);
    gload16(bg,          bs + wave * 512);
    if (TN == 128) gload16(bg + rowK64, bs + wave * 512 + 2048);
    ag += 32; bg += 32;
  };
  auto compute = [&](const ushort_t* ab, const ushort_t* bb) {
    s8v af[4], bf[JN];
    #pragma unroll
    for (int i = 0; i < 4; i++)
      af[i] = *(const s8v*)(ab + (wm + i * 16 + r) * 32 + quad * 8);
    #pragma unroll
    for (int j = 0; j < JN; j++)
      bf[j] = *(const s8v*)(bb + (wn + j * 16 + r) * 32 + quad * 8);
    #pragma unroll
    for (int i = 0; i < 4; i++)
      #pragma unroll
      for (int j = 0; j < JN; j++)
        acc[i][j] = MFMA16(af[i], bf[j], acc[i][j]);
  };

  stage(As0, Bs0);
  __syncthreads();
  const int R = (K >> 6) - 1;
  for (int it = 0; it < R; it++) {
    stage(As1, Bs1);
    compute(As0, Bs0);
    __syncthreads();
    stage(As0, Bs0);
    compute(As1, Bs1);
    __syncthreads();
  }
  stage(As1, Bs1);
  compute(As0, Bs0);
  __syncthreads();
  compute(As1, Bs1);

  const int bblk = m0 >> 11;
  float bj[JN], gj[JN];
  #pragma unroll
  for (int j = 0; j < JN; j++) {
    const int col = n0 + wn + j * 16 + r;
    bj[j] = (EPI == 2 || EPI == 3) ? bias[col] : 0.f;
    gj[j] = (EPI == 1 || EPI == 3) ? emb[bblk * 6144 + gate_off + col] : 0.f;
  }
  #pragma unroll
  for (int i = 0; i < 4; i++) {
    #pragma unroll
    for (int rr = 0; rr < 4; rr++) {
      const int row = m0 + wm + i * 16 + quad * 4 + rr;
      const size_t rbase = (size_t)row * N + n0 + wn;
      #pragma unroll
      for (int j = 0; j < JN; j++) {
        float v = acc[i][j][rr];
        const size_t idx = rbase + j * 16 + r;
        if (EPI == 0) {
          outb[idx] = f2bf(v);
        } else if (EPI == 1) {
          outf[idx] = resid[idx] + gj[j] * v;
        } else if (EPI == 2) {
          v += bj[j];
          const float t = fmaf(v * v, 0.1029436f, 2.3022083f);
          const float e = __builtin_amdgcn_exp2f(-v * t);
          outb[idx] = f2bf(v * __builtin_amdgcn_rcpf(1.f + e));
        } else {
          outf[idx] = resid[idx] + gj[j] * (v + bj[j]);
        }
      }
    }
  }
}

// ---------------------------------------------------------------------------
// 4c) gemm8p v2 (R7 best-measured): fine-interleave 8-phase, 256x256 tile,
//     BK=64, 512 threads = 8 waves (2M x 4N), dbuf LDS 128KB.
//     Used for QKV (EPI=0, grid 12x16) and FC1 (EPI=2, grid 16x16).
//     R9 A/B: QKV on gemm8p beats gemm_bt-full-fill by ~4 us despite 192
//     blocks on 256 CUs -- per-block schedule advantage > fill loss.
// ---------------------------------------------------------------------------
#define G8P(AB, BB, SDA, SDB, KO, STG, P)                                     \
  {                                                                           \
    s8v af0k0, af0k1, af1k0, af1k1;                                           \
    {                                                                         \
      const ushort_t* Ap0 = (AB) + (size_t)(wm + (2*(P)) * 16 + r) * 64;      \
      const ushort_t* Ap1 = (AB) + (size_t)(wm + (2*(P)+1) * 16 + r) * 64;    \
      af0k0 = *(const s8v*)(Ap0 + ((quad ^ rx) << 3));                        \
      af0k1 = *(const s8v*)(Ap0 + (((4 + quad) ^ rx) << 3));                  \
      af1k0 = *(const s8v*)(Ap1 + ((quad ^ rx) << 3));                        \
      af1k1 = *(const s8v*)(Ap1 + (((4 + quad) ^ rx) << 3));                  \
    }                                                                         \
    if ((P) == 0) {                                                           \
      _Pragma("unroll")                                                       \
      for (int j_ = 0; j_ < 4; j_++) {                                        \
        const ushort_t* Bp = (BB) + (size_t)(wn + j_ * 16 + r) * 64;          \
        bfv[j_][0] = *(const s8v*)(Bp + ((quad ^ rx) << 3));                  \
        bfv[j_][1] = *(const s8v*)(Bp + (((4 + quad) ^ rx) << 3));            \
      }                                                                       \
    }                                                                         \
    if (STG) {                                                                \
      gload16(ag + (KO) + (P) * row8K, (SDA) + (P) * 512);                    \
      gload16(bg + (KO) + (P) * row8K, (SDB) + (P) * 512);                    \
    }                                                                         \
    __builtin_amdgcn_s_barrier();                                             \
    asm volatile("s_waitcnt lgkmcnt(0)" ::: "memory");                        \
    __builtin_amdgcn_sched_barrier(0);                                        \
    __builtin_amdgcn_s_setprio(1);                                            \
    _Pragma("unroll")                                                         \
    for (int j_ = 0; j_ < 4; j_++) {                                          \
      acc[2*(P)][j_]     = MFMA16(af0k0, bfv[j_][0], acc[2*(P)][j_]);         \
      acc[2*(P)][j_]     = MFMA16(af0k1, bfv[j_][1], acc[2*(P)][j_]);         \
      acc[2*(P)+1][j_]   = MFMA16(af1k0, bfv[j_][0], acc[2*(P)+1][j_]);       \
      acc[2*(P)+1][j_]   = MFMA16(af1k1, bfv[j_][1], acc[2*(P)+1][j_]);       \
    }                                                                         \
    __builtin_amdgcn_s_setprio(0);                                            \
    __builtin_amdgcn_s_barrier();                                             \
  }

template<int EPI>
__launch_bounds__(512, 2)
__global__ void gemm8p(const ushort_t* __restrict__ A, const ushort_t* __restrict__ Bw,
                       int K, int N, ushort_t* __restrict__ outb,
                       const float* __restrict__ bias)
{
  __shared__ ushort_t Ash[2][256 * 64];   // [buf][row][chunk^(row&7)], 64KB
  __shared__ ushort_t Bsh[2][256 * 64];
  const int tid = threadIdx.x;
  const int wid = tid >> 6, lane = tid & 63;
  const int quad = lane >> 4, r = lane & 15, rx = r & 7;

  // T1: XCD-aware bijective block swizzle (nwg % 8 == 0 for our grids)
  const int nwg = gridDim.x * gridDim.y;
  int wg = blockIdx.y * gridDim.x + blockIdx.x;
  wg = (wg & 7) * (nwg >> 3) + (wg >> 3);
  const int bx = wg % gridDim.x, by = wg / gridDim.x;
  const int m0 = by * 256, n0 = bx * 256;
  const int wm = (wid >> 2) * 128;   // wave row base in tile
  const int wn = (wid & 3) * 64;     // wave col base in tile

  // staging: lane l covers row (l>>3), 16B slot (l&7); LDS slot s of row r
  // holds logical chunk s^(r&7) -> inverse-swizzle the global SOURCE col.
  const int srow = lane >> 3;
  const int scol = ((lane & 7) ^ srow) * 8;
  const ushort_t* ag = A  + (size_t)(m0 + wid * 32 + srow) * K + scol;
  const ushort_t* bg = Bw + (size_t)(n0 + wid * 32 + srow) * K + scol;
  const size_t row8K = (size_t)8 * K;

  ushort_t* A0d = &Ash[0][wid * 2048];
  ushort_t* B0d = &Bsh[0][wid * 2048];
  ushort_t* A1d = &Ash[1][wid * 2048];
  ushort_t* B1d = &Bsh[1][wid * 2048];

  f4v acc[8][4] = {};

  // prologue: stage tile 0 fully into buf0
  #pragma unroll
  for (int c = 0; c < 4; c++) {
    gload16(ag + c * row8K, A0d + c * 512);
    gload16(bg + c * row8K, B0d + c * 512);
  }
  __syncthreads();

  const int NT = K >> 6;   // even, >= 4 for our shapes
  #pragma unroll 1
  for (int t = 0; t < NT; t += 2) {
    {
      // tile t: compute buf0, stage t+1 -> buf1 (2 loads per phase)
      const ushort_t* Ab = &Ash[0][0];
      const ushort_t* Bb = &Bsh[0][0];
      const size_t ko = (size_t)(t + 1) * 64;
      s8v bfv[4][2];
      G8P(Ab, Bb, A1d, B1d, ko, true, 0);
      G8P(Ab, Bb, A1d, B1d, ko, true, 1);
      G8P(Ab, Bb, A1d, B1d, ko, true, 2);
      G8P(Ab, Bb, A1d, B1d, ko, true, 3);
      __syncthreads();   // drain: t+1's loads (issued ph0-3) + barrier
    }
    {
      // tile t+1: compute buf1, stage t+2 -> buf0 (if it exists)
      const ushort_t* Ab = &Ash[1][0];
      const ushort_t* Bb = &Bsh[1][0];
      const size_t ko = (size_t)(t + 2) * 64;
      const bool stg = (t + 2) < NT;
      s8v bfv[4][2];
      G8P(Ab, Bb, A0d, B0d, ko, stg, 0);
      G8P(Ab, Bb, A0d, B0d, ko, stg, 1);
      G8P(Ab, Bb, A0d, B0d, ko, stg, 2);
      G8P(Ab, Bb, A0d, B0d, ko, stg, 3);
      __syncthreads();
    }
  }

  // epilogue (row-outer, j-inner for full-line write combining)
  float bj[4];
  #pragma unroll
  for (int j = 0; j < 4; j++)
    bj[j] = (EPI == 2) ? bias[n0 + wn + j * 16 + r] : 0.f;
  #pragma unroll
  for (int i = 0; i < 8; i++) {
    #pragma unroll
    for (int rr = 0; rr < 4; rr++) {
      const int row = m0 + wm + i * 16 + quad * 4 + rr;
      const size_t rbase = (size_t)row * N + n0 + wn;
      #pragma unroll
      for (int j = 0; j < 4; j++) {
        float v = acc[i][j][rr];
        const size_t idx = rbase + j * 16 + r;
        if (EPI == 0) {
          outb[idx] = f2bf(v);
        } else {
          v += bj[j];
          const float tt = fmaf(v * v, 0.1029436f, 2.3022083f);
          const float e = __builtin_amdgcn_exp2f(-v * tt);
          outb[idx] = f2bf(v * __builtin_amdgcn_rcpf(1.f + e));
        }
      }
    }
  }
}

// ---------------------------------------------------------------------------
// 5) QKV post: RMSNorm + RoPE + layout for Q/K only (R10: V handled by
//    vtrans directly from the QKV buffer -- saves the VR round trip).
// ---------------------------------------------------------------------------
__launch_bounds__(256)
__global__ void qkv_post(const ushort_t* __restrict__ qkv, const float* __restrict__ rope,
                         const float* __restrict__ qw, const float* __restrict__ kw,
                         ushort_t* __restrict__ q_r, ushort_t* __restrict__ k_r)
{
  const int row = blockIdx.x, b = row >> 11, s = row & 2047, tid = threadIdx.x;
  const ushort_t* base = qkv + (size_t)row * 3072;
  const int c = tid * 4;
  s4v qv = *(const s4v*)(base + c);
  s4v kv = *(const s4v*)(base + 1024 + c);
  float qf[4], kf[4]; float sq = 0.f, sk = 0.f;
  #pragma unroll
  for (int i = 0; i < 4; i++) {
    qf[i] = bf2f((ushort_t)qv[i]); kf[i] = bf2f((ushort_t)kv[i]);
    sq += qf[i] * qf[i]; sk += kf[i] * kf[i];
  }
  #pragma unroll
  for (int m = 32; m; m >>= 1) { sq += __shfl_down(sq, m); sk += __shfl_down(sk, m); }
  __shared__ float red[8];
  const int wave = tid >> 6, lane = tid & 63;
  if (!lane) { red[wave] = sq; red[4 + wave] = sk; }
  __syncthreads();
  const float rq = rsqrtf((red[0]+red[1]+red[2]+red[3]) * (1.f/1024.f) + 1e-6f)
                   * 0.18033688011112042f;  // fold 0.125*log2(e) into Q
  const float rk = rsqrtf((red[4]+red[5]+red[6]+red[7]) * (1.f/1024.f) + 1e-6f);

  const int h = c >> 6, d = c & 63;
  const float* rp = rope + ((size_t)s * 64 + d) * 2;
  float4 r01 = *(const float4*)(rp);
  float4 r23 = *(const float4*)(rp + 4);
  const float q0 = qf[0]*rq*qw[c], q1 = qf[1]*rq*qw[c+1];
  const float q2 = qf[2]*rq*qw[c+2], q3 = qf[3]*rq*qw[c+3];
  const float k0 = kf[0]*rk*kw[c], k1 = kf[1]*rk*kw[c+1];
  const float k2 = kf[2]*rk*kw[c+2], k3 = kf[3]*rk*kw[c+3];
  s4v qo, ko;
  qo[0] = (short)f2bf(q0 * r01.x - q1 * r01.y);
  qo[1] = (short)f2bf(q1 * r01.z + q0 * r01.w);
  qo[2] = (short)f2bf(q2 * r23.x - q3 * r23.y);
  qo[3] = (short)f2bf(q3 * r23.z + q2 * r23.w);
  ko[0] = (short)f2bf(k0 * r01.x - k1 * r01.y);
  ko[1] = (short)f2bf(k1 * r01.z + k0 * r01.w);
  ko[2] = (short)f2bf(k2 * r23.x - k3 * r23.y);
  ko[3] = (short)f2bf(k3 * r23.z + k2 * r23.w);
  const size_t rowbase = ((size_t)(b * 16 + h) * 2048 + s) * 64;
  const int d_s = (((d >> 3) ^ (s & 7)) << 3) | (d & 7);   // K chunk swizzle
  *(s4v*)(q_r + rowbase + d) = qo;
  *(s4v*)(k_r + rowbase + d_s) = ko;
}

// ---------------------------------------------------------------------------
// 6) V transpose. R10: reads V directly from the QKV buffer (row stride
//    3072, V at col offset 2048 + h*64) -- VR intermediate eliminated.
//    Runs before rms3_mod (which reuses the QKV buffer as NM) -- safe.
// ---------------------------------------------------------------------------
__launch_bounds__(256)
__global__ void vtrans(const ushort_t* __restrict__ qkv, ushort_t* __restrict__ v_t)
{
  const int bh = blockIdx.x >> 5, st = blockIdx.x & 31;
  const int b = bh >> 4, h = bh & 15;
  const int s0 = st * 64;
  __shared__ ushort_t tile[64 * 72];
  const int tid = threadIdx.x;
  #pragma unroll
  for (int rep = 0; rep < 2; rep++) {
    const int idx = rep * 256 + tid;
    const int sr = idx >> 3, dc = (idx & 7) << 3;
    s8v val = *(const s8v*)(qkv + (size_t)(b * 2048 + s0 + sr) * 3072
                            + 2048 + h * 64 + dc);
    *(s8v*)(tile + sr * 72 + dc) = val;
  }
  __syncthreads();
  #pragma unroll
  for (int rep = 0; rep < 2; rep++) {
    const int idx = rep * 256 + tid;
    const int d = idx >> 3;
    const int scs = (((idx & 7) ^ (d & 7)) << 3);
    s8v val;
    const int sc = (idx & 7) << 3;
    #pragma unroll
    for (int j = 0; j < 8; j++) val[j] = (short)tile[(sc + j) * 72 + d];
    *(s8v*)(v_t + ((size_t)bh * 64 + d) * 2048 + s0 + scs) = val;
  }
}

// ---------------------------------------------------------------------------
// 7) Flash attention, v7 (frozen): KVBLK=64, K+V dbuf LDS 40KB,
//    4 blocks/CU, defer-max (T13).
// ---------------------------------------------------------------------------
__launch_bounds__(256, 4)
__global__ void flash(const ushort_t* __restrict__ q_r, const ushort_t* __restrict__ k_r,
                      const ushort_t* __restrict__ v_t, ushort_t* __restrict__ attn)
{
  __shared__ ushort_t Ksh[2][64 * 64];   // [key][d], 8 chunks ^(key&7), x2 dbuf
  __shared__ ushort_t Vsh[2][64 * 64];   // [d][key], 8 chunks pos = c^(d&7), x2 dbuf
  __shared__ ushort_t Psh[4][16 * 64];   // per-wave [q][key], chunk pos = c^(q&7)
  const int bh = blockIdx.x >> 5, qb = blockIdx.x & 31;
  const int tid = threadIdx.x, wave = tid >> 6, lane = tid & 63;
  const int quad = lane >> 4, r = lane & 15;
  const int rx = r & 7;
  const int q0 = qb * 64 + wave * 16;
  const size_t bhS = (size_t)bh * 2048;

  s8v aq0 = *(const s8v*)(q_r + (bhS + q0 + r) * 64 + quad * 8);
  s8v aq1 = *(const s8v*)(q_r + (bhS + q0 + r) * 64 + 32 + quad * 8);

  f4v o[4] = {};
  float mi = -1e30f, li = 0.f;

  // staging: per wave 16 K-rows (2 calls x 8 rows) and 16 V-rows (2 x 8)
  const ushort_t* kg = k_r + (bhS + wave * 16 + (lane >> 3)) * 64 + (lane & 7) * 8;
  const ushort_t* vg = v_t + ((size_t)bh * 64 + wave * 16 + (lane >> 3)) * 2048
                       + (lane & 7) * 8;
  const int klo = wave * 1024 + lane * 8;   // = wave-base + lane*16B
  const int vlo = wave * 1024 + lane * 8;
  ushort_t* pw = &Psh[wave][0];

  auto stage = [&](ushort_t* kbuf, ushort_t* vbuf, int kb) {
    #pragma unroll
    for (int c = 0; c < 2; c++) {
      gload16(kg + (size_t)(kb + c * 8) * 64, kbuf + klo + c * 512);
      gload16(vg + kb + (size_t)(c * 8) * 2048, vbuf + vlo + c * 512);
    }
  };

  // QK^T -> online softmax (defer-max) -> PV on one staged 64-key tile
  auto step = [&](const ushort_t* Kc, const ushort_t* Vc) {
    // S^T[key][q]: 4 row-tiles of 16 keys
    f4v st[4];
    __builtin_amdgcn_s_setprio(1);
    #pragma unroll
    for (int t = 0; t < 4; t++) {
      const ushort_t* krow = Kc + (t * 16 + r) * 64;
      s8v k0 = *(const s8v*)(krow + ((quad ^ rx) << 3));
      s8v k1 = *(const s8v*)(krow + (((4 + quad) ^ rx) << 3));
      f4v z = {};
      z = MFMA16(k0, aq0, z);
      z = MFMA16(k1, aq1, z);
      st[t] = z;
    }
    __builtin_amdgcn_s_setprio(0);

    // max: tree + 2 cross-lane hops
    float m4[4];
    #pragma unroll
    for (int t = 0; t < 4; t++)
      m4[t] = fmaxf(fmaxf(st[t][0], st[t][1]), fmaxf(st[t][2], st[t][3]));
    float mloc = fmaxf(fmaxf(m4[0], m4[1]), fmaxf(m4[2], m4[3]));
    mloc = fmaxf(mloc, __shfl_xor(mloc, 16));
    mloc = fmaxf(mloc, __shfl_xor(mloc, 32));

    // defer-max: if no q-row grew its max by > 8, keep old mi (skip rescale)
    const bool grow = !__all(mloc - mi <= 8.f);
    const float mref = grow ? fmaxf(mi, mloc) : mi;

    float p[4][4];
    uint2 pk[4];
    #pragma unroll
    for (int t = 0; t < 4; t++) {
      #pragma unroll
      for (int rr = 0; rr < 4; rr++)
        p[t][rr] = __builtin_amdgcn_exp2f(st[t][rr] - mref);
      const unsigned u0 = fbits(p[t][0]) + 0x8000u;
      const unsigned u1 = fbits(p[t][1]) + 0x8000u;
      const unsigned u2 = fbits(p[t][2]) + 0x8000u;
      const unsigned u3 = fbits(p[t][3]) + 0x8000u;
      pk[t].x = __builtin_amdgcn_perm(u1, u0, 0x07060302u);
      pk[t].y = __builtin_amdgcn_perm(u3, u2, 0x07060302u);
    }

    // pack P -> Psh (8 chunks, swizzled), b64 writes
    #pragma unroll
    for (int t = 0; t < 4; t++) {
      const int cw = t * 2 + (quad >> 1);     // logical chunk 0..7
      const int sc = cw ^ rx;
      *(uint2*)(pw + r * 64 + (sc << 3) + (quad & 1) * 4) = pk[t];
    }

    // rescale O only when the running max actually moved
    if (grow) {
      const float al = __builtin_amdgcn_exp2f(mi - mref);
      float alo[4];
      #pragma unroll
      for (int rr = 0; rr < 4; rr++) alo[rr] = __shfl(al, quad * 4 + rr);
      #pragma unroll
      for (int nt = 0; nt < 4; nt++)
        #pragma unroll
        for (int rr = 0; rr < 4; rr++) o[nt][rr] *= alo[rr];
      li *= al;
      mi = mref;
    }

    // sum: tree + 2 hops
    float s4r[4];
    #pragma unroll
    for (int t = 0; t < 4; t++)
      s4r[t] = (p[t][0] + p[t][1]) + (p[t][2] + p[t][3]);
    float ls = (s4r[0] + s4r[1]) + (s4r[2] + s4r[3]);
    ls += __shfl_xor(ls, 16);
    ls += __shfl_xor(ls, 32);
    li += ls;

    asm volatile("s_waitcnt lgkmcnt(0)" ::: "memory");  // P writes -> reads, same wave

    // O += P * V  (K = 32 keys per MFMA, 2 chunks of the 64-key tile)
    __builtin_amdgcn_s_setprio(1);
    #pragma unroll
    for (int kc = 0; kc < 2; kc++) {
      const int c = kc * 4 + quad;           // logical chunk 0..7
      const int sc = c ^ rx;
      s8v ap = *(const s8v*)(pw + r * 64 + (sc << 3));
      #pragma unroll
      for (int nt = 0; nt < 4; nt++) {
        s8v bv = *(const s8v*)(Vc + (nt * 16 + r) * 64 + (sc << 3));
        o[nt] = MFMA16(ap, bv, o[nt]);
      }
    }
    __builtin_amdgcn_s_setprio(0);
  };

  // prologue: stage tile 0; __syncthreads drains vmcnt(0) + barrier
  stage(Ksh[0], Vsh[0], 0);
  __syncthreads();

  // 32 tiles, 2 per iteration (static buffer indices).
  #pragma unroll 1
  for (int kb = 0; kb < 2048; kb += 128) {
    stage(Ksh[1], Vsh[1], kb + 64);
    step(Ksh[0], Vsh[0]);
    __syncthreads();
    if (kb + 128 < 2048) stage(Ksh[0], Vsh[0], kb + 128);
    step(Ksh[1], Vsh[1]);
    __syncthreads();
  }

  const int h = bh & 15, b = bh >> 4;
  const float linv = 1.f / li;
  #pragma unroll
  for (int rr = 0; rr < 4; rr++) {
    const float inv = __shfl(linv, quad * 4 + rr);
    const size_t orow = ((size_t)(b * 2048 + q0 + quad * 4 + rr)) * 1024 + h * 64;
    #pragma unroll
    for (int nt = 0; nt < 4; nt++)
      attn[orow + nt * 16 + r] = f2bf(o[nt][rr] * inv);
  }
}

// ---------------------------------------------------------------------------
// 8) RMSNorm3 + mlp modulation -> nm bf16
// ---------------------------------------------------------------------------
__launch_bounds__(256)
__global__ void rms3_mod(const float* __restrict__ h, const float* __restrict__ emb,
                         const float* __restrict__ w3, ushort_t* __restrict__ nm)
{
  const int row = blockIdx.x, b = row >> 11, tid = threadIdx.x;
  const float* hr = h + (size_t)row * 1024;
  const int c = tid * 4;
  float4 v = *(const float4*)(hr + c);
  float s2 = v.x*v.x + v.y*v.y + v.z*v.z + v.w*v.w;
  #pragma unroll
  for (int m = 32; m; m >>= 1) s2 += __shfl_down(s2, m);
  __shared__ float red[4];
  const int wave = tid >> 6, lane = tid & 63;
  if (!lane) red[wave] = s2;
  __syncthreads();
  const float rms = rsqrtf((red[0] + red[1] + red[2] + red[3]) * (1.f / 1024.f) + 1e-6f);
  const float* sh = emb + b * 6144 + 3072;
  const float* sc = emb + b * 6144 + 4096;
  float4 shv = *(const float4*)(sh + c);
  float4 scv = *(const float4*)(sc + c);
  float4 wv  = *(const float4*)(w3 + c);
  s4v ov;
  ov[0] = (short)f2bf(v.x * rms * wv.x * (1.f + scv.x) + shv.x);
  ov[1] = (short)f2bf(v.y * rms * wv.y * (1.f + scv.y) + shv.y);
  ov[2] = (short)f2bf(v.z * rms * wv.z * (1.f + scv.z) + shv.z);
  ov[3] = (short)f2bf(v.w * rms * wv.w * (1.f + scv.w) + shv.w);
  *(s4v*)(nm + (size_t)row * 1024 + c) = ov;
}

// ---------------------------------------------------------------------------
// host launcher
// ---------------------------------------------------------------------------
extern "C" void kernel_launch(void* const* d_in, const int* in_sizes, int n_in,
                              void* d_out, int out_size, void* d_ws, size_t ws_size,
                              hipStream_t stream)
{
  const float* x    = (const float*)d_in[0];
  const float* ts   = (const float*)d_in[1];
  const float* rope = (const float*)d_in[2];
  const float* adw  = (const float*)d_in[3];
  const float* adb  = (const float*)d_in[4];
  const float* wq   = (const float*)d_in[5];
  const float* wk   = (const float*)d_in[6];
  const float* wv   = (const float*)d_in[7];
  const float* wo   = (const float*)d_in[8];
  const float* qnw  = (const float*)d_in[9];
  const float* knw  = (const float*)d_in[10];
  const float* n3w  = (const float*)d_in[11];
  const float* f1w  = (const float*)d_in[12];
  const float* f1b  = (const float*)d_in[13];
  const float* f2w  = (const float*)d_in[14];
  const float* f2b  = (const float*)d_in[15];

  char* ws = (char*)d_ws;
  ushort_t* WQKV = (ushort_t*)(ws + 0);          //  6 MB
  ushort_t* WO   = (ushort_t*)(ws + 6291456);    //  2 MB
  ushort_t* F1   = (ushort_t*)(ws + 8388608);    //  8 MB
  ushort_t* F2   = (ushort_t*)(ws + 16777216);   //  8 MB
  float*    EMB  = (float*)   (ws + 25165824);   //  48 KB
  float*    H    = (float*)   (ws + 25214976);   // 16 MB
  ushort_t* XM   = (ushort_t*)(ws + 41992192);   //  8 MB  (later: ATTN)
  ushort_t* QKV  = (ushort_t*)(ws + 50380800);   // 24 MB  (later: NM)
  ushort_t* QR   = (ushort_t*)(ws + 75546624);   //  8 MB  (later: FF1 spans 32MB)
  ushort_t* KR   = (ushort_t*)(ws + 83935232);   //  8 MB
  ushort_t* VT   = (ushort_t*)(ws + 100712448);  //  8 MB
  ushort_t* ATTN = XM;
  ushort_t* NM   = QKV;
  ushort_t* FF1  = QR;

  convert_w<<<12288, 256, 0, stream>>>(wq, wk, wv, wo, f1w, f2w, WQKV, WO, F1, F2);
  adaln<<<1536, 256, 0, stream>>>(ts, adw, adb, EMB);
  ln_mod<<<4096, 256, 0, stream>>>(x, EMB, XM);
  gemm8p<0><<<dim3(12, 16), 512, 0, stream>>>(XM, WQKV, 1024, 3072, QKV, nullptr);
  qkv_post<<<4096, 256, 0, stream>>>(QKV, rope, qnw, knw, QR, KR);
  vtrans<<<1024, 256, 0, stream>>>(QKV, VT);
  flash<<<1024, 256, 0, stream>>>(QR, KR, VT, ATTN);
  gemm_bt<1, 64><<<dim3(16, 32), 256, 0, stream>>>(ATTN, WO, 1024, 1024,
      nullptr, H, nullptr, x, EMB, 2048);
  rms3_mod<<<4096, 256, 0, stream>>>(H, EMB, n3w, NM);
  gemm8p<2><<<dim3(16, 16), 512, 0, stream>>>(NM, F1, 1024, 4096, FF1, f1b);
  gemm_bt<3, 64><<<dim3(16, 32), 256, 0, stream>>>(FF1, F2, 4096, 1024,
      nullptr, (float*)d_out, f2b, H, EMB, 5120);
}